// Round 7
// baseline (684.139 us; speedup 1.0000x reference)
//
#include <hip/hip_runtime.h>
#include <hip/hip_bf16.h>
#include <math.h>

#define N_NODES 10000
#define N_EDGES 20000
#define EPAD 20224
#define N_GRAPHS 64
#define DIM 64
#define NFEAT 32
#define EDIM 16
#define NCLS 10

typedef short short8 __attribute__((ext_vector_type(8)));
typedef float f32x16 __attribute__((ext_vector_type(16)));

static __device__ __forceinline__ short f2b(float f) {
  __hip_bfloat16 h = __float2bfloat16(f);
  return __builtin_bit_cast(short, h);
}

// ---- pack all 5 layers' w2(+b2 rows) into 32x32x16 B-fragment order ----
// short8 at [S*128 + n*64 + l] holds B[S*16 + (l>>5)*8 + u][n*32 + (l&31)].
__global__ __launch_bounds__(256) void k_pack_all(
    const float* __restrict__ w20, const float* __restrict__ b20,
    const float* __restrict__ w2c, const float* __restrict__ b2c,
    short* __restrict__ pk, float* __restrict__ gpool) {
  const int b = blockIdx.x, t = threadIdx.x;
  if (b == 0) { for (int i = t; i < N_GRAPHS * DIM; i += 256) gpool[i] = 0.f; }
  __shared__ float tile[32][65];
  const float *w2, *b2; short* out; int K, lb;
  if (b < 129) { w2 = w20; b2 = b20; out = pk; K = 4096; lb = b; }
  else {
    int bb = b - 129; int k = bb / 258; lb = bb % 258;
    w2 = w2c + (size_t)k * 8192 * 64; b2 = b2c + (size_t)k * 4096;
    out = pk + 264192 + (size_t)k * 528384; K = 8192;
  }
  #pragma unroll
  for (int it = 0; it < 2; ++it) {
    int idx = t + it * 256;
    int r = idx >> 4, c4 = idx & 15;
    int k = lb * 32 + r;
    const float* sp = (k < K) ? (w2 + (size_t)k * 64 + c4 * 4)
                              : (b2 + (size_t)(k - K) * 64 + c4 * 4);
    float4 v = *(const float4*)sp;
    float* dr = &tile[r][c4 * 4];
    dr[0] = v.x; dr[1] = v.y; dr[2] = v.z; dr[3] = v.w;
  }
  __syncthreads();
  const int S_local = t >> 7, n = (t >> 6) & 1, l = t & 63;
  const int rbase = S_local * 16 + ((l >> 5) << 3);
  const int col = n * 32 + (l & 31);
  short8 o;
  #pragma unroll
  for (int u = 0; u < 8; ++u) o[u] = f2b(tile[rbase + u][col]);
  ((short8*)out)[(size_t)lb * 256 + t] = o;
}

// ---- fused edge_feat + layer-0 edge MLP (writes h1T[j][e]) ----
__global__ __launch_bounds__(256) void k_ef_mlp1(
    const float* __restrict__ ea, const float* __restrict__ etw,
    const float* __restrict__ etb, const float* __restrict__ w1,
    const float* __restrict__ b1, float* __restrict__ e_feat,
    float* __restrict__ h1T) {
  __shared__ float sea[8][17];
  __shared__ float se[8][65];
  const int b = blockIdx.x, t = threadIdx.x;
  const int e0 = b * 8;
  if (t < 128) {
    int r = t >> 4, c = t & 15;
    sea[r][c] = ea[(size_t)(e0 + r) * EDIM + c];
  }
  __syncthreads();
  {
    int o = t & 63, eh = t >> 6;
    #pragma unroll
    for (int k = 0; k < 2; ++k) {
      int r = eh * 2 + k;
      float a = etb[o];
      #pragma unroll
      for (int i = 0; i < EDIM; ++i) a = fmaf(sea[r][i], etw[i * 64 + o], a);
      se[r][o] = a;
      e_feat[(size_t)(e0 + r) * 64 + o] = a;
    }
  }
  __syncthreads();
  {
    int j = t & 127, eh = t >> 7;
    int r0 = eh * 4;
    float a0 = b1[j], a1 = a0, a2 = a0, a3 = a0;
    #pragma unroll 8
    for (int i = 0; i < 64; ++i) {
      float wv = w1[i * 128 + j];
      a0 = fmaf(se[r0 + 0][i], wv, a0);
      a1 = fmaf(se[r0 + 1][i], wv, a1);
      a2 = fmaf(se[r0 + 2][i], wv, a2);
      a3 = fmaf(se[r0 + 3][i], wv, a3);
    }
    float4 o = {fmaxf(a0, 0.f), fmaxf(a1, 0.f), fmaxf(a2, 0.f), fmaxf(a3, 0.f)};
    *(float4*)(h1T + (size_t)j * EPAD + e0 + r0) = o;
  }
}

// ---- layer-0 root init; also zeroes part0 ----
__global__ __launch_bounds__(256) void k_root0(const float* __restrict__ x,
    const float* __restrict__ rootw, const float* __restrict__ rootb,
    float* __restrict__ agg, double* __restrict__ part0) {
  if (blockIdx.x == 0 && threadIdx.x < 128) part0[threadIdx.x] = 0.0;
  int idx = blockIdx.x * 256 + threadIdx.x;
  if (idx >= N_NODES * DIM) return;
  int n = idx >> 6, o = idx & 63;
  float a = rootb[o];
  const float* hr = x + (size_t)n * NFEAT;
  #pragma unroll 8
  for (int i = 0; i < NFEAT; ++i) a = fmaf(hr[i], rootw[i * 64 + o], a);
  agg[idx] = a;
}

// ---- implicit-A MFMA msg GEMM, 32x32x16, register-resident B ----
// Block = 4 waves, 64 edges; wave w owns K-quarter (j in [w*32, w*32+32)).
// No barriers in K-loop: B + h loads are plain global loads, compiler-
// scheduled 2-deep pipeline. Cross-wave reduce in LDS, 1 atomicAdd/elem.
template<int IN>
__global__ __launch_bounds__(256, 2) void k_msg(
    const float* __restrict__ h1T, const float* __restrict__ xin,
    const int* __restrict__ src, const int* __restrict__ dst,
    const short* __restrict__ pk, float* __restrict__ agg) {
  constexpr int QW = IN / 16;            // k-windows per j: 2 (L0) / 4
  constexpr int JR = 32;                 // j's per wave (128/4 waves)
  __shared__ float red[4][64][68];       // pad 68: conflict-free reduce
  const int t = threadIdx.x, l = t & 63, w = t >> 6;
  const int e0 = blockIdx.x * 64;
  const int jbase = w * JR;
  const int col = l & 31;
  const int h8 = (l >> 5) << 3;
  const short8* B = (const short8*)pk;

  // x fragments (whole-K resident): xr[m][q][u] = x[src[e_m]][q*16+h8+u]
  float xr[2][QW][8];
  #pragma unroll
  for (int m = 0; m < 2; ++m) {
    int eme = e0 + m * 32 + col;
    int srow = src[eme < N_EDGES ? eme : 0];
    #pragma unroll
    for (int q = 0; q < QW; ++q) {
      const float* xp = xin + (size_t)srow * IN + q * 16 + h8;
      float4 a = *(const float4*)xp;
      float4 bq = *(const float4*)(xp + 4);
      xr[m][q][0] = a.x;  xr[m][q][1] = a.y;  xr[m][q][2] = a.z;  xr[m][q][3] = a.w;
      xr[m][q][4] = bq.x; xr[m][q][5] = bq.y; xr[m][q][6] = bq.z; xr[m][q][7] = bq.w;
    }
  }

  f32x16 acc00 = {}, acc01 = {}, acc10 = {}, acc11 = {};

  short8 bufA[QW * 2], bufB[QW * 2];
  float2 hA, hB;

#define LOADB(buf, j)                                              \
  { int S0_ = (j) * QW;                                            \
    _Pragma("unroll")                                              \
    for (int q = 0; q < QW; ++q) {                                 \
      buf[q * 2]     = B[(size_t)(S0_ + q) * 128 + l];             \
      buf[q * 2 + 1] = B[(size_t)(S0_ + q) * 128 + 64 + l];        \
    } }
#define LOADH(hv, j)                                               \
  { hv.x = h1T[(size_t)(j) * EPAD + e0 + col];                     \
    hv.y = h1T[(size_t)(j) * EPAD + e0 + 32 + col]; }
#define COMPUTE(buf, hv)                                           \
  { _Pragma("unroll")                                              \
    for (int q = 0; q < QW; ++q) {                                 \
      short8 av0, av1;                                             \
      _Pragma("unroll")                                            \
      for (int u = 0; u < 8; ++u) {                                \
        av0[u] = f2b(hv.x * xr[0][q][u]);                          \
        av1[u] = f2b(hv.y * xr[1][q][u]);                          \
      }                                                            \
      acc00 = __builtin_amdgcn_mfma_f32_32x32x16_bf16(av0, buf[q*2],   acc00, 0, 0, 0); \
      acc01 = __builtin_amdgcn_mfma_f32_32x32x16_bf16(av0, buf[q*2+1], acc01, 0, 0, 0); \
      acc10 = __builtin_amdgcn_mfma_f32_32x32x16_bf16(av1, buf[q*2],   acc10, 0, 0, 0); \
      acc11 = __builtin_amdgcn_mfma_f32_32x32x16_bf16(av1, buf[q*2+1], acc11, 0, 0, 0); \
    } }

  LOADB(bufA, jbase); LOADH(hA, jbase);
  for (int g = 0; g < JR; g += 2) {
    LOADB(bufB, jbase + g + 1); LOADH(hB, jbase + g + 1);
    COMPUTE(bufA, hA);
    if (g + 2 < JR) { LOADB(bufA, jbase + g + 2); LOADH(hA, jbase + g + 2); }
    COMPUTE(bufB, hB);
  }
  if (w == 0) {  // bias rows: A = x directly; S = 8*IN + q = 128*QW + q
    LOADB(bufA, 128);
    #pragma unroll
    for (int q = 0; q < QW; ++q) {
      short8 av0, av1;
      #pragma unroll
      for (int u = 0; u < 8; ++u) {
        av0[u] = f2b(xr[0][q][u]);
        av1[u] = f2b(xr[1][q][u]);
      }
      acc00 = __builtin_amdgcn_mfma_f32_32x32x16_bf16(av0, bufA[q*2],   acc00, 0, 0, 0);
      acc01 = __builtin_amdgcn_mfma_f32_32x32x16_bf16(av0, bufA[q*2+1], acc01, 0, 0, 0);
      acc10 = __builtin_amdgcn_mfma_f32_32x32x16_bf16(av1, bufA[q*2],   acc10, 0, 0, 0);
      acc11 = __builtin_amdgcn_mfma_f32_32x32x16_bf16(av1, bufA[q*2+1], acc11, 0, 0, 0);
    }
  }
#undef LOADB
#undef LOADH
#undef COMPUTE

  // C/D (m74/m101): col = lane&31, row = (v&3)+8*(v>>2)+4*(lane>>5)
  #pragma unroll
  for (int v = 0; v < 16; ++v) {
    int r = (v & 3) + ((v >> 2) << 3) + ((l >> 5) << 2);
    red[w][r][col]           = acc00[v];
    red[w][r][col + 32]      = acc01[v];
    red[w][r + 32][col]      = acc10[v];
    red[w][r + 32][col + 32] = acc11[v];
  }
  __syncthreads();

  // sum 4 wave-partials, one atomicAdd per element
  const int row = t >> 2, cq = (t & 3) * 16;
  const int e = e0 + row;
  if (e < N_EDGES) {
    float* ap = agg + (size_t)dst[e] * 64 + cq;
    #pragma unroll
    for (int cc = 0; cc < 4; ++cc) {
      float4 s0 = *(const float4*)&red[0][row][cq + cc * 4];
      float4 s1 = *(const float4*)&red[1][row][cq + cc * 4];
      float4 s2 = *(const float4*)&red[2][row][cq + cc * 4];
      float4 s3 = *(const float4*)&red[3][row][cq + cc * 4];
      atomicAdd(ap + cc * 4 + 0, s0.x + s1.x + s2.x + s3.x);
      atomicAdd(ap + cc * 4 + 1, s0.y + s1.y + s2.y + s3.y);
      atomicAdd(ap + cc * 4 + 2, s0.z + s1.z + s2.z + s3.z);
      atomicAdd(ap + cc * 4 + 3, s0.w + s1.w + s2.w + s3.w);
    }
  }
}

// ---- BN partial sums (coalesced, f64 atomics into part[0..127]) ----
__global__ __launch_bounds__(256) void k_bnpart(const float* __restrict__ agg,
    double* __restrict__ part) {
  const int t = threadIdx.x;
  const int c = t & 63, rg = t >> 6;
  const int r0 = blockIdx.x * 50;
  const int r1 = min(r0 + 50, N_NODES);
  double s = 0.0, s2 = 0.0;
  for (int r = r0 + rg; r < r1; r += 4) {
    float v = agg[(size_t)r * 64 + c];
    s += v;
    s2 += (double)v * v;
  }
  __shared__ double shs[4][64];
  __shared__ double shq[4][64];
  shs[rg][c] = s; shq[rg][c] = s2;
  __syncthreads();
  if (t < 64) {
    double ts = shs[0][t] + shs[1][t] + shs[2][t] + shs[3][t];
    double tq = shq[0][t] + shq[1][t] + shq[2][t] + shq[3][t];
    atomicAdd(&part[t], ts);
    atomicAdd(&part[64 + t], tq);
  }
}

// ---- fused: bnapply(k)[+resid]->h_cur; root(k+1)->agg; mlp1(k+1)->h1T ----
__global__ __launch_bounds__(256) void k_inter(
    const float* __restrict__ agg, const double* __restrict__ part,
    const float* __restrict__ gamma, const float* __restrict__ beta,
    const float* resid, float* __restrict__ hout,
    const float* __restrict__ rootw, const float* __restrict__ rootb,
    float* __restrict__ aggn, double* __restrict__ partn,
    const float* __restrict__ ef, const float* __restrict__ w1,
    const float* __restrict__ b1, float* __restrict__ h1T) {
  const int b = blockIdx.x, t = threadIdx.x;
  if (b < 157) {
    __shared__ float sh[64][65];
    if (b == 0 && t < 128) partn[t] = 0.0;
    const int o = t & 63, rg = t >> 6;
    const int n0 = b * 64;
    float m = (float)(part[o] * (1.0 / N_NODES));
    float s2 = (float)(part[64 + o] * (1.0 / N_NODES));
    float inv = 1.0f / sqrtf(s2 - m * m + 1e-5f);
    float sc = gamma[o] * inv;
    float sf = beta[o] - m * sc;
    #pragma unroll
    for (int k = 0; k < 16; ++k) {
      int r = rg * 16 + k;
      int n = n0 + r;
      float v = 0.f;
      if (n < N_NODES) {
        v = fmaxf(fmaf(agg[(size_t)n * 64 + o], sc, sf), 0.f);
        if (resid) v += resid[(size_t)n * 64 + o];
        hout[(size_t)n * 64 + o] = v;
      }
      sh[r][o] = v;
    }
    __syncthreads();
    float acc[16];
    float rb = rootb[o];
    #pragma unroll
    for (int k = 0; k < 16; ++k) acc[k] = rb;
    for (int i = 0; i < 64; ++i) {
      float wv = rootw[i * 64 + o];
      #pragma unroll
      for (int k = 0; k < 16; ++k) acc[k] = fmaf(sh[rg * 16 + k][i], wv, acc[k]);
    }
    #pragma unroll
    for (int k = 0; k < 16; ++k) {
      int n = n0 + rg * 16 + k;
      if (n < N_NODES) aggn[(size_t)n * 64 + o] = acc[k];
    }
  } else {
    const int e0 = (b - 157) * 8;
    __shared__ float se[8][65];
    {
      int r = t >> 5, ci = (t & 31) * 2;
      const float* sp = ef + (size_t)(e0 + r) * 64 + ci;
      se[r][ci] = sp[0];
      se[r][ci + 1] = sp[1];
    }
    __syncthreads();
    const int j = t & 127, eh = t >> 7;
    const int r0 = eh * 4;
    float a0 = b1[j], a1 = a0, a2 = a0, a3 = a0;
    #pragma unroll 8
    for (int i = 0; i < 64; ++i) {
      float wv = w1[i * 128 + j];
      a0 = fmaf(se[r0 + 0][i], wv, a0);
      a1 = fmaf(se[r0 + 1][i], wv, a1);
      a2 = fmaf(se[r0 + 2][i], wv, a2);
      a3 = fmaf(se[r0 + 3][i], wv, a3);
    }
    float4 o = {fmaxf(a0, 0.f), fmaxf(a1, 0.f), fmaxf(a2, 0.f), fmaxf(a3, 0.f)};
    *(float4*)(h1T + (size_t)j * EPAD + e0 + r0) = o;
  }
}

// ---- final: bnapply(4) + resid + global_max_pool ----
__global__ __launch_bounds__(256) void k_final(const float* __restrict__ agg,
    const double* __restrict__ part, const float* __restrict__ gamma,
    const float* __restrict__ beta, const float* __restrict__ resid,
    const int* __restrict__ batch, float* __restrict__ gpool) {
  int idx = blockIdx.x * 256 + threadIdx.x;
  if (idx >= N_NODES * DIM) return;
  int c = idx & 63, r = idx >> 6;
  float m = (float)(part[c] * (1.0 / N_NODES));
  float s2 = (float)(part[64 + c] * (1.0 / N_NODES));
  float inv = 1.0f / sqrtf(s2 - m * m + 1e-5f);
  float sc = gamma[c] * inv;
  float sf = beta[c] - m * sc;
  float v = fmaxf(fmaf(agg[idx], sc, sf), 0.f) + resid[idx];
  atomicMax((unsigned int*)&gpool[batch[r] * 64 + c], __float_as_uint(v));
}

// ---- head: per-graph MLP chain ----
__global__ __launch_bounds__(64) void k_head(const float* __restrict__ g,
    const float* __restrict__ w1, const float* __restrict__ b1,
    const float* __restrict__ w2, const float* __restrict__ b2,
    const float* __restrict__ wo, const float* __restrict__ bo,
    float* __restrict__ out) {
  __shared__ float s0[64];
  __shared__ float s1[64];
  const int r = blockIdx.x, t = threadIdx.x;
  s0[t] = g[r * 64 + t];
  __syncthreads();
  float a = b1[t];
  #pragma unroll 8
  for (int i = 0; i < 64; ++i) a = fmaf(s0[i], w1[i * 64 + t], a);
  s1[t] = fmaxf(a, 0.f);
  __syncthreads();
  a = b2[t];
  #pragma unroll 8
  for (int i = 0; i < 64; ++i) a = fmaf(s1[i], w2[i * 64 + t], a);
  __syncthreads();
  s0[t] = fmaxf(a, 0.f);
  __syncthreads();
  if (t < NCLS) {
    float o = bo[t];
    #pragma unroll 8
    for (int i = 0; i < 64; ++i) o = fmaf(s0[i], wo[i * NCLS + t], o);
    out[r * NCLS + t] = 1.f / (1.f + expf(-o));
  }
}

extern "C" void kernel_launch(void* const* d_in, const int* in_sizes, int n_in,
                              void* d_out, int out_size, void* d_ws, size_t ws_size,
                              hipStream_t stream) {
  const float* x          = (const float*)d_in[0];
  const int*   eidx       = (const int*)d_in[1];
  const float* eattr      = (const float*)d_in[2];
  const int*   batch      = (const int*)d_in[3];
  const float* et_w       = (const float*)d_in[4];
  const float* et_b       = (const float*)d_in[5];
  const float* nn1_w1     = (const float*)d_in[6];
  const float* nn1_b1     = (const float*)d_in[7];
  const float* nn1_w2     = (const float*)d_in[8];
  const float* nn1_b2     = (const float*)d_in[9];
  const float* root_in    = (const float*)d_in[10];
  const float* bias_in    = (const float*)d_in[11];
  const float* convs_w1   = (const float*)d_in[12];
  const float* convs_b1   = (const float*)d_in[13];
  const float* convs_w2   = (const float*)d_in[14];
  const float* convs_b2   = (const float*)d_in[15];
  const float* convs_root = (const float*)d_in[16];
  const float* convs_bias = (const float*)d_in[17];
  const float* bn_gamma   = (const float*)d_in[18];
  const float* bn_beta    = (const float*)d_in[19];
  const float* lin1_w     = (const float*)d_in[20];
  const float* lin1_b     = (const float*)d_in[21];
  const float* lin2_w     = (const float*)d_in[22];
  const float* lin2_b     = (const float*)d_in[23];
  const float* lout_w     = (const float*)d_in[24];
  const float* lout_b     = (const float*)d_in[25];

  const int* srcp = eidx;
  const int* dstp = eidx + N_EDGES;

  double* part0 = (double*)d_ws;                 // 128 doubles
  double* part1 = part0 + 128;                   // 128 doubles
  float* e_feat = (float*)(part0 + 256);         // E*64
  float* h1T    = e_feat + N_EDGES * DIM;        // 128*EPAD (transposed)
  float* agg    = h1T + 128 * EPAD;              // N*64
  float* h_cur  = agg + N_NODES * DIM;           // N*64
  float* g      = h_cur + N_NODES * DIM;         // 64*64
  short* pk0    = (short*)(g + N_GRAPHS * DIM);
  short* pkL[4];
  for (int k = 0; k < 4; ++k) pkL[k] = pk0 + 264192 + (size_t)k * 528384;
  double* parts[2] = {part0, part1};

  const int gMsg = (N_EDGES + 63) / 64;          // 313

  k_pack_all<<<1161, 256, 0, stream>>>(nn1_w2, nn1_b2, convs_w2, convs_b2, pk0, g);
  k_ef_mlp1<<<2500, 256, 0, stream>>>(eattr, et_w, et_b, nn1_w1, nn1_b1,
                                      e_feat, h1T);
  k_root0<<<2500, 256, 0, stream>>>(x, root_in, bias_in, agg, part0);

  // layer 0
  k_msg<NFEAT><<<gMsg, 256, 0, stream>>>(h1T, x, srcp, dstp, pk0, agg);
  k_bnpart<<<200, 256, 0, stream>>>(agg, part0);

  for (int k = 0; k < 4; ++k) {
    k_inter<<<2657, 256, 0, stream>>>(
        agg, parts[k & 1], bn_gamma + k * 64, bn_beta + k * 64,
        (k == 0) ? nullptr : h_cur, h_cur,
        convs_root + (size_t)k * 4096, convs_bias + (size_t)k * 64,
        agg, parts[(k + 1) & 1],
        e_feat, convs_w1 + (size_t)k * 64 * 128, convs_b1 + (size_t)k * 128, h1T);
    k_msg<DIM><<<gMsg, 256, 0, stream>>>(h1T, h_cur, srcp, dstp, pkL[k], agg);
    k_bnpart<<<200, 256, 0, stream>>>(agg, parts[(k + 1) & 1]);
  }

  k_final<<<2500, 256, 0, stream>>>(agg, parts[0], bn_gamma + 4 * 64,
                                    bn_beta + 4 * 64, h_cur, batch, g);
  k_head<<<N_GRAPHS, 64, 0, stream>>>(g, lin1_w, lin1_b, lin2_w, lin2_b,
                                      lout_w, lout_b, (float*)d_out);
}